// Round 9
// baseline (151.854 us; speedup 1.0000x reference)
//
#include <hip/hip_runtime.h>
#include <hip/hip_bf16.h>

namespace {

constexpr int T = 4, H = 128, W = 128, C = 256, HD = 8, K = 9, F = 32;
constexpr int M = T * H * W;  // 65536

typedef __attribute__((ext_vector_type(8))) short short8v;   // 8 bf16 (4 VGPR)
typedef __attribute__((ext_vector_type(4))) float f32x4;     // MFMA acc

__device__ __forceinline__ unsigned short f2bf(float f) {
  unsigned u = __float_as_uint(f);
  unsigned r = (u + 0x7fffu + ((u >> 16) & 1u)) >> 16;
  return (unsigned short)r;
}

__device__ __forceinline__ float bf2f(unsigned short u) {
  return __uint_as_float(((unsigned)u) << 16);
}

// ---------------------------------------------------------------------------
// Templated MFMA GEMM: Cout[m][n] = sum_k A[m][k] * B[n][k]  (+ bias[n])
// ALAYOUT: 0 = fp32 row-major [M][256]
//          3 = bf16 plane-split [fh:2][head:8][M][16] (k = head*32+fh*16+e)
// ---------------------------------------------------------------------------
template <int ALAYOUT, bool OUT_F32>
__global__ __launch_bounds__(256) void mfma_gemm(
    const void* __restrict__ Aptr, const float* __restrict__ Bw,
    void* __restrict__ Cptr, const float* __restrict__ bias) {
  __shared__ unsigned short As[128][40];
  __shared__ unsigned short Bs[128][40];
  const int m0 = blockIdx.x * 128;
  const int n0 = blockIdx.y * 128;
  const int t = threadIdx.x;
  const int lane = t & 63;
  const int wid = t >> 6;
  const int wm = wid >> 1, wn = wid & 1;
  const int fr = lane & 15;
  const int kg = lane >> 4;

  f32x4 acc[4][4];
#pragma unroll
  for (int ni = 0; ni < 4; ++ni) {
    float b = 0.f;
    if (OUT_F32) b = bias[n0 + wn * 64 + ni * 16 + fr];
#pragma unroll
    for (int mi = 0; mi < 4; ++mi) {
      acc[mi][ni][0] = b; acc[mi][ni][1] = b;
      acc[mi][ni][2] = b; acc[mi][ni][3] = b;
    }
  }

  for (int k0 = 0; k0 < C; k0 += 32) {
    __syncthreads();
    if (ALAYOUT == 3) {
      const unsigned short* Ab = (const unsigned short*)Aptr;
      const int hidx = k0 >> 5;
#pragma unroll
      for (int i = 0; i < 2; ++i) {
        const int flat = t + i * 256;          // 0..511
        const int row = flat >> 2, q = flat & 3;   // q = 16B piece 0..3
        const int plane = q >> 1;
        const int e0 = (q & 1) * 8;
        *(short8v*)&As[row][q * 8] = *(const short8v*)(
            Ab + ((size_t)(plane * 8 + hidx) * M + (m0 + row)) * 16 + e0);
      }
    } else {
      const float* Af = (const float*)Aptr;
#pragma unroll
      for (int i = 0; i < 4; ++i) {
        const int flat = t + i * 256;          // 0..1023
        const int row = flat >> 3, kc = (flat & 7) * 4;
        const float4 v4 = *(const float4*)(Af + (size_t)(m0 + row) * C + k0 + kc);
        ushort4 o;
        o.x = f2bf(v4.x); o.y = f2bf(v4.y); o.z = f2bf(v4.z); o.w = f2bf(v4.w);
        *(ushort4*)&As[row][kc] = o;
      }
    }
#pragma unroll
    for (int i = 0; i < 4; ++i) {
      const int flat = t + i * 256;
      const int row = flat >> 3, kc = (flat & 7) * 4;
      const float4 v4 = *(const float4*)(Bw + (size_t)(n0 + row) * C + k0 + kc);
      ushort4 o;
      o.x = f2bf(v4.x); o.y = f2bf(v4.y); o.z = f2bf(v4.z); o.w = f2bf(v4.w);
      *(ushort4*)&Bs[row][kc] = o;
    }
    __syncthreads();
    short8v af[4], bfv[4];
#pragma unroll
    for (int mi = 0; mi < 4; ++mi)
      af[mi] = *(const short8v*)&As[wm * 64 + mi * 16 + fr][kg * 8];
#pragma unroll
    for (int ni = 0; ni < 4; ++ni)
      bfv[ni] = *(const short8v*)&Bs[wn * 64 + ni * 16 + fr][kg * 8];
#pragma unroll
    for (int mi = 0; mi < 4; ++mi)
#pragma unroll
      for (int ni = 0; ni < 4; ++ni)
        acc[mi][ni] = __builtin_amdgcn_mfma_f32_16x16x32_bf16(
            af[mi], bfv[ni], acc[mi][ni], 0, 0, 0);
  }

#pragma unroll
  for (int mi = 0; mi < 4; ++mi) {
#pragma unroll
    for (int ni = 0; ni < 4; ++ni) {
      const int gcol = n0 + wn * 64 + ni * 16 + fr;
#pragma unroll
      for (int r = 0; r < 4; ++r) {
        const int grow = m0 + wm * 64 + mi * 16 + kg * 4 + r;
        if (OUT_F32) {
          ((float*)Cptr)[(size_t)grow * C + gcol] = acc[mi][ni][r];
        } else {
          ((unsigned short*)Cptr)[(size_t)grow * C + gcol] = f2bf(acc[mi][ni][r]);
        }
      }
    }
  }
}

// ---------------------------------------------------------------------------
// Gather v8: block = (8x8 tile, head), 512 threads.
//  - VGPR staging (reverted from global_load_lds: its scattered 16B requests
//    produced ~120MB parasitic TCC WRITE, r7/r8), ALL 6 pieces batched in
//    ONE latency epoch (fixes r6's 13-sequential-piece serialization).
//  - fh mapped INSIDE the wave (lane<32 fh0, lane>=32 fh1 of same pair):
//    metadata loaded once per pair by lower half-wave, handed to upper half
//    via __shfl — no duplicate flow/attn traffic (r7/r8's +60MB FETCH).
//  - 50KB LDS, launch_bounds(512,6): 3 blocks x 8 waves = 24 waves/CU.
//  - plane-split agg2 [fh][head][M][16]: dense wave store stream.
// ---------------------------------------------------------------------------
struct __attribute__((packed, aligned(4))) I4p { int a, b, c, d; };
struct __attribute__((packed, aligned(4))) I2p { int a, b; };
struct __attribute__((packed, aligned(4))) F4p { float a, b, c, d; };

__global__ __launch_bounds__(512, 6) void gather_lds_kernel(
    const unsigned short* __restrict__ v, const float* __restrict__ attn,
    const int* __restrict__ flows, unsigned short* __restrict__ agg2) {
  __shared__ __align__(16) unsigned short halo[4 * 14 * 14 * 32];  // 50176 B
  // bijective XCD-chunk swizzle: 2048 blocks = 8 XCDs x 256; head fastest.
  const int nb = (blockIdx.x & 7) * 256 + (blockIdx.x >> 3);
  const int head = nb & 7;
  const int tile = nb >> 3;          // 0..255 over 16x16 grid of 8x8 tiles
  const int h0 = (tile >> 4) * 8;
  const int w0 = (tile & 15) * 8;
  const int tid = threadIdx.x;
  const int lane = tid & 63;
  const int sp = lane & 31;          // pair-in-wave
  const int fh = lane >> 5;          // f-half 0/1
  const int p = (tid >> 6) * 32 + sp;  // pair 0..255
  const int s = p & 63;
  const int tq = p >> 6;
  const int h = h0 + (s >> 3);
  const int w = w0 + (s & 7);
  const int m = (tq << 14) | (h << 7) | w;

  // ---- metadata loads: lower half-wave only, issued first ----
  I4p f0, f1, f2, f3, f4, f5; I2p f6; int f7; F4p a0, a1; float a2;
  const int base = ((head << 16) | m) * K;
  const int fb = base * 3;
  if (fh == 0) {
    f0 = *(const I4p*)(flows + fb + 0);
    f1 = *(const I4p*)(flows + fb + 4);
    f2 = *(const I4p*)(flows + fb + 8);
    f3 = *(const I4p*)(flows + fb + 12);
    f4 = *(const I4p*)(flows + fb + 16);
    f5 = *(const I4p*)(flows + fb + 20);
    f6 = *(const I2p*)(flows + fb + 24);
    f7 = flows[fb + 26];
    a0 = *(const F4p*)(attn + base + 0);
    a1 = *(const F4p*)(attn + base + 4);
    a2 = attn[base + 8];
  }

  // ---- stage halo: 3136 x 16B pieces; 6 per thread, one batched epoch ----
  const unsigned short* vhead = v + head * F;
  auto piece_src = [&](int pi, int& ldsoff) -> const short8v* {
    const int sliver = pi >> 2, j = pi & 3;
    const int tt = sliver / 196;
    const int rem = sliver - tt * 196;
    const int hh = rem / 14;
    const int ww = rem - hh * 14;
    const int hc = min(max(h0 - 3 + hh, 0), H - 1);
    const int wc = min(max(w0 - 3 + ww, 0), W - 1);
    const int sm = (tt << 14) | (hc << 7) | wc;
    ldsoff = sliver * 32 + (j ^ (sliver & 3)) * 8;  // swizzled LDS dest
    return (const short8v*)(vhead + (size_t)sm * C + j * 8);  // linear src
  };
  {
    int lo0, lo1, lo2, lo3, lo4, lo5;
    const short8v* s0 = piece_src(tid, lo0);
    const short8v* s1 = piece_src(512 + tid, lo1);
    const short8v* s2 = piece_src(1024 + tid, lo2);
    const short8v* s3 = piece_src(1536 + tid, lo3);
    const short8v* s4 = piece_src(2048 + tid, lo4);
    const short8v* s5 = piece_src(2560 + tid, lo5);
    const short8v pA = *s0, pB = *s1, pC = *s2, pD = *s3, pE = *s4, pF = *s5;
    *(short8v*)&halo[lo0] = pA;
    *(short8v*)&halo[lo1] = pB;
    *(short8v*)&halo[lo2] = pC;
    *(short8v*)&halo[lo3] = pD;
    *(short8v*)&halo[lo4] = pE;
    *(short8v*)&halo[lo5] = pF;
    if (tid < 64) {  // tail pieces 3072..3135
      int lo6;
      const short8v* s6 = piece_src(3072 + tid, lo6);
      *(short8v*)&halo[lo6] = *s6;
    }
  }

  // ---- decode (lower half), hand to upper half via shuffles ----
  int rowv[9]; float awv[9];
  if (fh == 0) {
    const int d[27] = {f0.a, f0.b, f0.c, f0.d, f1.a, f1.b, f1.c, f1.d,
                       f2.a, f2.b, f2.c, f2.d, f3.a, f3.b, f3.c, f3.d,
                       f4.a, f4.b, f4.c, f4.d, f5.a, f5.b, f5.c, f5.d,
                       f6.a, f6.b, f7};
    const float awt[9] = {a0.a, a0.b, a0.c, a0.d, a1.a, a1.b, a1.c, a1.d, a2};
#pragma unroll
    for (int k = 0; k < 9; ++k) {
      const int ts = min(max(tq + d[3 * k + 0], 0), T - 1);
      const int hs = min(max(h + d[3 * k + 1], 0), H - 1) - (h0 - 3);
      const int ws = min(max(w + d[3 * k + 2], 0), W - 1) - (w0 - 3);
      rowv[k] = (ts * 14 + hs) * 14 + ws;
      awv[k] = awt[k];
    }
  } else {
#pragma unroll
    for (int k = 0; k < 9; ++k) { rowv[k] = 0; awv[k] = 0.f; }
  }
#pragma unroll
  for (int k = 0; k < 9; ++k) {
    rowv[k] = __shfl(rowv[k], sp, 64);
    awv[k] = __shfl(awv[k], sp, 64);
  }
  __syncthreads();

  // ---- weighted sum from LDS (this lane's 16-elem f-half) ----
  float acc[16];
#pragma unroll
  for (int i = 0; i < 16; ++i) acc[i] = 0.f;
#pragma unroll
  for (int k = 0; k < 9; ++k) {
    const int rbase = rowv[k] * 32;
    const int rsw = rowv[k] & 3;
#pragma unroll
    for (int jl = 0; jl < 2; ++jl) {
      const int j = fh * 2 + jl;
      const short8v pp = *(const short8v*)&halo[rbase + (j ^ rsw) * 8];
#pragma unroll
      for (int e = 0; e < 8; ++e)
        acc[jl * 8 + e] += awv[k] * bf2f((unsigned short)pp[e]);
    }
  }

  // ---- store plane-split: agg2[fh][head][M][16] — dense wave stream ----
  unsigned short* dst = agg2 + ((size_t)(fh * 8 + head) * M + m) * 16;
#pragma unroll
  for (int jl = 0; jl < 2; ++jl) {
    short8v o;
#pragma unroll
    for (int e = 0; e < 8; ++e) o[e] = (short)f2bf(acc[jl * 8 + e]);
    *(short8v*)(dst + jl * 8) = o;
  }
}

// ---------------------------------------------------------------------------
// Fallback (ws too small): fused gather + fp32 proj GEMM. Proven.
// ---------------------------------------------------------------------------
__global__ __launch_bounds__(256) void agg_proj_kernel(
    const unsigned short* __restrict__ v, const float* __restrict__ attn,
    const int* __restrict__ flows, const float* __restrict__ proj_w,
    const float* __restrict__ proj_b, float* __restrict__ out) {
  __shared__ float Agg[32][C];
  __shared__ float Bs[32][C];
  const int bid = blockIdx.x;
  const int t = bid >> 9;
  const int h0 = ((bid >> 5) & 15) * 8;
  const int w0 = (bid & 31) * 4;
  const int tid = threadIdx.x;

  const int g = tid >> 3;
  const int f4 = (tid & 7) * 4;
#pragma unroll
  for (int r = 0; r < 8; ++r) {
    const int pi = r * 32 + g;
    const int pos = pi >> 3;
    const int head = pi & 7;
    const int h = h0 + (pos >> 2);
    const int w = w0 + (pos & 3);
    const int base = (((head * T + t) * H + h) * W + w) * K;
    const int fbase = base * 3;
    float4 acc = {0.f, 0.f, 0.f, 0.f};
#pragma unroll
    for (int k = 0; k < K; ++k) {
      const int dt = flows[fbase + k * 3 + 0];
      const int dh = flows[fbase + k * 3 + 1];
      const int dw = flows[fbase + k * 3 + 2];
      const float aw = attn[base + k];
      const int tt = min(max(t + dt, 0), T - 1);
      const int hh = min(max(h + dh, 0), H - 1);
      const int ww = min(max(w + dw, 0), W - 1);
      const int mm = (tt * H + hh) * W + ww;
      const ushort4 r4 = *(const ushort4*)(v + (size_t)mm * C + head * F + f4);
      acc.x += aw * bf2f(r4.x);
      acc.y += aw * bf2f(r4.y);
      acc.z += aw * bf2f(r4.z);
      acc.w += aw * bf2f(r4.w);
    }
    *(float4*)&Agg[pos][head * F + f4] = acc;
  }
  __syncthreads();

  const int tx = tid & 31;
  const int ty = tid >> 5;
  float acc2[4][8];
  {
    const float4 b0 = *(const float4*)(proj_b + tx * 8);
    const float4 b1 = *(const float4*)(proj_b + tx * 8 + 4);
#pragma unroll
    for (int i = 0; i < 4; ++i) {
      acc2[i][0] = b0.x; acc2[i][1] = b0.y; acc2[i][2] = b0.z; acc2[i][3] = b0.w;
      acc2[i][4] = b1.x; acc2[i][5] = b1.y; acc2[i][6] = b1.z; acc2[i][7] = b1.w;
    }
  }
  for (int k0 = 0; k0 < C; k0 += 32) {
#pragma unroll
    for (int i = 0; i < 8; ++i) {
      const float4 w4 = *(const float4*)(proj_w + (size_t)tid * C + k0 + i * 4);
      Bs[i * 4 + 0][tid] = w4.x;
      Bs[i * 4 + 1][tid] = w4.y;
      Bs[i * 4 + 2][tid] = w4.z;
      Bs[i * 4 + 3][tid] = w4.w;
    }
    __syncthreads();
#pragma unroll 4
    for (int kk = 0; kk < 32; ++kk) {
      const float4 bb0 = *(const float4*)&Bs[kk][tx * 8];
      const float4 bb1 = *(const float4*)&Bs[kk][tx * 8 + 4];
      float a[4];
#pragma unroll
      for (int i = 0; i < 4; ++i) a[i] = Agg[ty * 4 + i][k0 + kk];
#pragma unroll
      for (int i = 0; i < 4; ++i) {
        acc2[i][0] += a[i] * bb0.x;
        acc2[i][1] += a[i] * bb0.y;
        acc2[i][2] += a[i] * bb0.z;
        acc2[i][3] += a[i] * bb0.w;
        acc2[i][4] += a[i] * bb1.x;
        acc2[i][5] += a[i] * bb1.y;
        acc2[i][6] += a[i] * bb1.z;
        acc2[i][7] += a[i] * bb1.w;
      }
    }
    __syncthreads();
  }
#pragma unroll
  for (int i = 0; i < 4; ++i) {
    const int pos = ty * 4 + i;
    const int h = h0 + (pos >> 2);
    const int w = w0 + (pos & 3);
    const int m = (t * H + h) * W + w;
    float4 o0, o1;
    o0.x = acc2[i][0]; o0.y = acc2[i][1]; o0.z = acc2[i][2]; o0.w = acc2[i][3];
    o1.x = acc2[i][4]; o1.y = acc2[i][5]; o1.z = acc2[i][6]; o1.w = acc2[i][7];
    *(float4*)(out + (size_t)m * C + tx * 8) = o0;
    *(float4*)(out + (size_t)m * C + tx * 8 + 4) = o1;
  }
}

}  // namespace

extern "C" void kernel_launch(void* const* d_in, const int* in_sizes, int n_in,
                              void* d_out, int out_size, void* d_ws,
                              size_t ws_size, hipStream_t stream) {
  const float* x = (const float*)d_in[0];
  const float* attn = (const float*)d_in[1];
  const int* flows = (const int*)d_in[2];
  const float* v_w = (const float*)d_in[3];
  const float* proj_w = (const float*)d_in[4];
  const float* proj_b = (const float*)d_in[5];
  float* out = (float*)d_out;

  const size_t VBYTES = (size_t)M * C * 2;  // 32 MB bf16
  unsigned short* v = (unsigned short*)d_ws;

  dim3 g1(M / 128, C / 128);
  mfma_gemm<0, false><<<g1, 256, 0, stream>>>(x, v_w, v, nullptr);

  if (ws_size >= 2 * VBYTES) {
    unsigned short* agg2 = (unsigned short*)((char*)d_ws + VBYTES);
    gather_lds_kernel<<<2048, 512, 0, stream>>>(v, attn, flows, agg2);
    mfma_gemm<3, true><<<g1, 256, 0, stream>>>(agg2, proj_w, out, proj_b);
  } else {
    const int nblk = T * (H / 8) * (W / 4);  // 2048
    agg_proj_kernel<<<nblk, 256, 0, stream>>>(v, attn, flows, proj_w, proj_b,
                                              out);
  }
}

// Round 10
// 96.607 us; speedup vs baseline: 1.5719x; 1.5719x over previous
//
#include <hip/hip_runtime.h>
#include <hip/hip_bf16.h>

namespace {

constexpr int T = 4, H = 128, W = 128, C = 256, HD = 8, K = 9, F = 32;
constexpr int M = T * H * W;  // 65536

typedef __attribute__((ext_vector_type(8))) short short8v;   // 8 bf16 (4 VGPR)
typedef __attribute__((ext_vector_type(4))) float f32x4;     // MFMA acc

__device__ __forceinline__ unsigned short f2bf(float f) {
  unsigned u = __float_as_uint(f);
  unsigned r = (u + 0x7fffu + ((u >> 16) & 1u)) >> 16;
  return (unsigned short)r;
}

__device__ __forceinline__ float bf2f(unsigned short u) {
  return __uint_as_float(((unsigned)u) << 16);
}

// ---------------------------------------------------------------------------
// Templated MFMA GEMM: Cout[m][n] = sum_k A[m][k] * B[n][k]  (+ bias[n])
// ALAYOUT: 0 = fp32 row-major [M][256]; 2 = bf16 head-major [head][M][32]
// ---------------------------------------------------------------------------
template <int ALAYOUT, bool OUT_F32>
__global__ __launch_bounds__(256) void mfma_gemm(
    const void* __restrict__ Aptr, const float* __restrict__ Bw,
    void* __restrict__ Cptr, const float* __restrict__ bias) {
  __shared__ unsigned short As[128][40];
  __shared__ unsigned short Bs[128][40];
  const int m0 = blockIdx.x * 128;
  const int n0 = blockIdx.y * 128;
  const int t = threadIdx.x;
  const int lane = t & 63;
  const int wid = t >> 6;
  const int wm = wid >> 1, wn = wid & 1;
  const int fr = lane & 15;
  const int kg = lane >> 4;

  f32x4 acc[4][4];
#pragma unroll
  for (int ni = 0; ni < 4; ++ni) {
    float b = 0.f;
    if (OUT_F32) b = bias[n0 + wn * 64 + ni * 16 + fr];
#pragma unroll
    for (int mi = 0; mi < 4; ++mi) {
      acc[mi][ni][0] = b; acc[mi][ni][1] = b;
      acc[mi][ni][2] = b; acc[mi][ni][3] = b;
    }
  }

  for (int k0 = 0; k0 < C; k0 += 32) {
    __syncthreads();
    if (ALAYOUT == 2) {
      const unsigned short* Ab = (const unsigned short*)Aptr;
      const size_t hb = (size_t)(k0 >> 5) * M * 32;
#pragma unroll
      for (int i = 0; i < 2; ++i) {
        const int flat = t + i * 256;          // 0..511
        const int row = flat >> 2, kc = (flat & 3) * 8;
        *(short8v*)&As[row][kc] =
            *(const short8v*)(Ab + hb + (size_t)(m0 + row) * 32 + kc);
      }
    } else {
      const float* Af = (const float*)Aptr;
#pragma unroll
      for (int i = 0; i < 4; ++i) {
        const int flat = t + i * 256;          // 0..1023
        const int row = flat >> 3, kc = (flat & 7) * 4;
        const float4 v4 = *(const float4*)(Af + (size_t)(m0 + row) * C + k0 + kc);
        ushort4 o;
        o.x = f2bf(v4.x); o.y = f2bf(v4.y); o.z = f2bf(v4.z); o.w = f2bf(v4.w);
        *(ushort4*)&As[row][kc] = o;
      }
    }
#pragma unroll
    for (int i = 0; i < 4; ++i) {
      const int flat = t + i * 256;
      const int row = flat >> 3, kc = (flat & 7) * 4;
      const float4 v4 = *(const float4*)(Bw + (size_t)(n0 + row) * C + k0 + kc);
      ushort4 o;
      o.x = f2bf(v4.x); o.y = f2bf(v4.y); o.z = f2bf(v4.z); o.w = f2bf(v4.w);
      *(ushort4*)&Bs[row][kc] = o;
    }
    __syncthreads();
    short8v af[4], bfv[4];
#pragma unroll
    for (int mi = 0; mi < 4; ++mi)
      af[mi] = *(const short8v*)&As[wm * 64 + mi * 16 + fr][kg * 8];
#pragma unroll
    for (int ni = 0; ni < 4; ++ni)
      bfv[ni] = *(const short8v*)&Bs[wn * 64 + ni * 16 + fr][kg * 8];
#pragma unroll
    for (int mi = 0; mi < 4; ++mi)
#pragma unroll
      for (int ni = 0; ni < 4; ++ni)
        acc[mi][ni] = __builtin_amdgcn_mfma_f32_16x16x32_bf16(
            af[mi], bfv[ni], acc[mi][ni], 0, 0, 0);
  }

#pragma unroll
  for (int mi = 0; mi < 4; ++mi) {
#pragma unroll
    for (int ni = 0; ni < 4; ++ni) {
      const int gcol = n0 + wn * 64 + ni * 16 + fr;
#pragma unroll
      for (int r = 0; r < 4; ++r) {
        const int grow = m0 + wm * 64 + mi * 16 + kg * 4 + r;
        if (OUT_F32) {
          ((float*)Cptr)[(size_t)grow * C + gcol] = acc[mi][ni][r];
        } else {
          ((unsigned short*)Cptr)[(size_t)grow * C + gcol] = f2bf(acc[mi][ni][r]);
        }
      }
    }
  }
}

// ---------------------------------------------------------------------------
// Gather v9 = round-6 structure (counter-proven clean: FETCH 65 / WRITE 33)
// with the staging loop batched into 2 latency epochs instead of 13 serial
// load->ds_write iterations. 256 threads, __launch_bounds__(256,4): 128-VGPR
// cap, no spill (r7-r9's 160MB phantom WRITE was scratch spill at VGPR=40).
// Thread = one (spatial, t) output, all 32 f. Head-major agg2 [head][M][32].
// ---------------------------------------------------------------------------
struct __attribute__((packed, aligned(4))) I4p { int a, b, c, d; };
struct __attribute__((packed, aligned(4))) I2p { int a, b; };
struct __attribute__((packed, aligned(4))) F4p { float a, b, c, d; };

__global__ __launch_bounds__(256, 4) void gather_lds_kernel(
    const unsigned short* __restrict__ v, const float* __restrict__ attn,
    const int* __restrict__ flows, unsigned short* __restrict__ agg2) {
  __shared__ __align__(16) unsigned short halo[4 * 14 * 14 * 32];  // 50176 B
  // bijective XCD-chunk swizzle: 2048 blocks = 8 XCDs x 256; head fastest.
  const int nb = (blockIdx.x & 7) * 256 + (blockIdx.x >> 3);
  const int head = nb & 7;
  const int tile = nb >> 3;          // 0..255 over 16x16 grid of 8x8 tiles
  const int h0 = (tile >> 4) * 8;
  const int w0 = (tile & 15) * 8;
  const int tid = threadIdx.x;
  const int s = tid & 63;            // spatial 0..63
  const int tq = tid >> 6;           // output t-plane 0..3
  const int h = h0 + (s >> 3);
  const int w = w0 + (s & 7);
  const int m = (tq << 14) | (h << 7) | w;

  // ---- metadata loads issued first (latency hides under staging) ----
  const int base = ((head << 16) | m) * K;
  const int fb = base * 3;
  const I4p f0 = *(const I4p*)(flows + fb + 0);
  const I4p f1 = *(const I4p*)(flows + fb + 4);
  const I4p f2 = *(const I4p*)(flows + fb + 8);
  const I4p f3 = *(const I4p*)(flows + fb + 12);
  const I4p f4 = *(const I4p*)(flows + fb + 16);
  const I4p f5 = *(const I4p*)(flows + fb + 20);
  const I2p f6 = *(const I2p*)(flows + fb + 24);
  const int f7 = flows[fb + 26];
  const F4p a0 = *(const F4p*)(attn + base + 0);
  const F4p a1 = *(const F4p*)(attn + base + 4);
  const float a2 = attn[base + 8];

  // ---- stage halo: 3136 x 16B pieces, batched in 2 epochs ----
  const unsigned short* vhead = v + head * F;
  auto piece_src = [&](int pi, int& ldsoff) -> const short8v* {
    const int sliver = pi >> 2, j = pi & 3;
    const int tt = sliver / 196;
    const int rem = sliver - tt * 196;
    const int hh = rem / 14;
    const int ww = rem - hh * 14;
    const int hc = min(max(h0 - 3 + hh, 0), H - 1);
    const int wc = min(max(w0 - 3 + ww, 0), W - 1);
    const int sm = (tt << 14) | (hc << 7) | wc;
    ldsoff = sliver * 32 + (j ^ (sliver & 3)) * 8;  // swizzled LDS dest
    return (const short8v*)(vhead + (size_t)sm * C + j * 8);  // linear src
  };
  {  // epoch A: pieces 0..1791 (7 per thread, one batched wait)
    short8v pc[7]; int lo[7];
#pragma unroll
    for (int it = 0; it < 7; ++it) pc[it] = *piece_src(tid + it * 256, lo[it]);
#pragma unroll
    for (int it = 0; it < 7; ++it) *(short8v*)&halo[lo[it]] = pc[it];
  }
  {  // epoch B: pieces 1792..3071 (5 per thread) + tail 3072..3135
    short8v pc[5]; int lo[5];
#pragma unroll
    for (int it = 0; it < 5; ++it)
      pc[it] = *piece_src(1792 + tid + it * 256, lo[it]);
    short8v pt; int lot = 0;
    if (tid < 64) pt = *piece_src(3072 + tid, lot);
#pragma unroll
    for (int it = 0; it < 5; ++it) *(short8v*)&halo[lo[it]] = pc[it];
    if (tid < 64) *(short8v*)&halo[lot] = pt;
  }
  __syncthreads();

  // ---- decode offsets -> halo rows ----
  const int d[27] = {f0.a, f0.b, f0.c, f0.d, f1.a, f1.b, f1.c, f1.d,
                     f2.a, f2.b, f2.c, f2.d, f3.a, f3.b, f3.c, f3.d,
                     f4.a, f4.b, f4.c, f4.d, f5.a, f5.b, f5.c, f5.d,
                     f6.a, f6.b, f7};
  const float aw[9] = {a0.a, a0.b, a0.c, a0.d, a1.a, a1.b, a1.c, a1.d, a2};
  int row[9];
#pragma unroll
  for (int k = 0; k < 9; ++k) {
    const int ts = min(max(tq + d[3 * k + 0], 0), T - 1);
    const int hs = min(max(h + d[3 * k + 1], 0), H - 1) - (h0 - 3);
    const int ws = min(max(w + d[3 * k + 2], 0), W - 1) - (w0 - 3);
    row[k] = (ts * 14 + hs) * 14 + ws;
  }

  // ---- weighted sum from LDS ----
  float acc[32];
#pragma unroll
  for (int i = 0; i < 32; ++i) acc[i] = 0.f;
#pragma unroll
  for (int k = 0; k < 9; ++k) {
    const int rbase = row[k] * 32;
    const int rsw = row[k] & 3;
#pragma unroll
    for (int j = 0; j < 4; ++j) {
      const short8v p = *(const short8v*)&halo[rbase + (j ^ rsw) * 8];
#pragma unroll
      for (int e = 0; e < 8; ++e)
        acc[j * 8 + e] += aw[k] * bf2f((unsigned short)p[e]);
    }
  }

  // ---- store head-major: agg2[head][M][F], 64B contiguous per thread ----
  unsigned short* dst = agg2 + ((size_t)head * M + m) * F;
#pragma unroll
  for (int j = 0; j < 4; ++j) {
    short8v o;
#pragma unroll
    for (int e = 0; e < 8; ++e) o[e] = (short)f2bf(acc[j * 8 + e]);
    *(short8v*)(dst + j * 8) = o;
  }
}

// ---------------------------------------------------------------------------
// Fallback (ws too small): fused gather + fp32 proj GEMM. Proven.
// ---------------------------------------------------------------------------
__global__ __launch_bounds__(256) void agg_proj_kernel(
    const unsigned short* __restrict__ v, const float* __restrict__ attn,
    const int* __restrict__ flows, const float* __restrict__ proj_w,
    const float* __restrict__ proj_b, float* __restrict__ out) {
  __shared__ float Agg[32][C];
  __shared__ float Bs[32][C];
  const int bid = blockIdx.x;
  const int t = bid >> 9;
  const int h0 = ((bid >> 5) & 15) * 8;
  const int w0 = (bid & 31) * 4;
  const int tid = threadIdx.x;

  const int g = tid >> 3;
  const int f4 = (tid & 7) * 4;
#pragma unroll
  for (int r = 0; r < 8; ++r) {
    const int pi = r * 32 + g;
    const int pos = pi >> 3;
    const int head = pi & 7;
    const int h = h0 + (pos >> 2);
    const int w = w0 + (pos & 3);
    const int base = (((head * T + t) * H + h) * W + w) * K;
    const int fbase = base * 3;
    float4 acc = {0.f, 0.f, 0.f, 0.f};
#pragma unroll
    for (int k = 0; k < K; ++k) {
      const int dt = flows[fbase + k * 3 + 0];
      const int dh = flows[fbase + k * 3 + 1];
      const int dw = flows[fbase + k * 3 + 2];
      const float aw = attn[base + k];
      const int tt = min(max(t + dt, 0), T - 1);
      const int hh = min(max(h + dh, 0), H - 1);
      const int ww = min(max(w + dw, 0), W - 1);
      const int mm = (tt * H + hh) * W + ww;
      const ushort4 r4 = *(const ushort4*)(v + (size_t)mm * C + head * F + f4);
      acc.x += aw * bf2f(r4.x);
      acc.y += aw * bf2f(r4.y);
      acc.z += aw * bf2f(r4.z);
      acc.w += aw * bf2f(r4.w);
    }
    *(float4*)&Agg[pos][head * F + f4] = acc;
  }
  __syncthreads();

  const int tx = tid & 31;
  const int ty = tid >> 5;
  float acc2[4][8];
  {
    const float4 b0 = *(const float4*)(proj_b + tx * 8);
    const float4 b1 = *(const float4*)(proj_b + tx * 8 + 4);
#pragma unroll
    for (int i = 0; i < 4; ++i) {
      acc2[i][0] = b0.x; acc2[i][1] = b0.y; acc2[i][2] = b0.z; acc2[i][3] = b0.w;
      acc2[i][4] = b1.x; acc2[i][5] = b1.y; acc2[i][6] = b1.z; acc2[i][7] = b1.w;
    }
  }
  for (int k0 = 0; k0 < C; k0 += 32) {
#pragma unroll
    for (int i = 0; i < 8; ++i) {
      const float4 w4 = *(const float4*)(proj_w + (size_t)tid * C + k0 + i * 4);
      Bs[i * 4 + 0][tid] = w4.x;
      Bs[i * 4 + 1][tid] = w4.y;
      Bs[i * 4 + 2][tid] = w4.z;
      Bs[i * 4 + 3][tid] = w4.w;
    }
    __syncthreads();
#pragma unroll 4
    for (int kk = 0; kk < 32; ++kk) {
      const float4 bb0 = *(const float4*)&Bs[kk][tx * 8];
      const float4 bb1 = *(const float4*)&Bs[kk][tx * 8 + 4];
      float a[4];
#pragma unroll
      for (int i = 0; i < 4; ++i) a[i] = Agg[ty * 4 + i][k0 + kk];
#pragma unroll
      for (int i = 0; i < 4; ++i) {
        acc2[i][0] += a[i] * bb0.x;
        acc2[i][1] += a[i] * bb0.y;
        acc2[i][2] += a[i] * bb0.z;
        acc2[i][3] += a[i] * bb0.w;
        acc2[i][4] += a[i] * bb1.x;
        acc2[i][5] += a[i] * bb1.y;
        acc2[i][6] += a[i] * bb1.z;
        acc2[i][7] += a[i] * bb1.w;
      }
    }
    __syncthreads();
  }
#pragma unroll
  for (int i = 0; i < 4; ++i) {
    const int pos = ty * 4 + i;
    const int h = h0 + (pos >> 2);
    const int w = w0 + (pos & 3);
    const int m = (t * H + h) * W + w;
    float4 o0, o1;
    o0.x = acc2[i][0]; o0.y = acc2[i][1]; o0.z = acc2[i][2]; o0.w = acc2[i][3];
    o1.x = acc2[i][4]; o1.y = acc2[i][5]; o1.z = acc2[i][6]; o1.w = acc2[i][7];
    *(float4*)(out + (size_t)m * C + tx * 8) = o0;
    *(float4*)(out + (size_t)m * C + tx * 8 + 4) = o1;
  }
}

}  // namespace

extern "C" void kernel_launch(void* const* d_in, const int* in_sizes, int n_in,
                              void* d_out, int out_size, void* d_ws,
                              size_t ws_size, hipStream_t stream) {
  const float* x = (const float*)d_in[0];
  const float* attn = (const float*)d_in[1];
  const int* flows = (const int*)d_in[2];
  const float* v_w = (const float*)d_in[3];
  const float* proj_w = (const float*)d_in[4];
  const float* proj_b = (const float*)d_in[5];
  float* out = (float*)d_out;

  const size_t VBYTES = (size_t)M * C * 2;  // 32 MB bf16
  unsigned short* v = (unsigned short*)d_ws;

  dim3 g1(M / 128, C / 128);
  mfma_gemm<0, false><<<g1, 256, 0, stream>>>(x, v_w, v, nullptr);

  if (ws_size >= 2 * VBYTES) {
    unsigned short* agg2 = (unsigned short*)((char*)d_ws + VBYTES);
    gather_lds_kernel<<<2048, 256, 0, stream>>>(v, attn, flows, agg2);
    mfma_gemm<2, true><<<g1, 256, 0, stream>>>(agg2, proj_w, out, proj_b);
  } else {
    const int nblk = T * (H / 8) * (W / 4);  // 2048
    agg_proj_kernel<<<nblk, 256, 0, stream>>>(v, attn, flows, proj_w, proj_b,
                                              out);
  }
}